// Round 13
// baseline (31.192 us; speedup 1.0000x reference)
//
#include <hip/hip_runtime.h>
#include <stdint.h>

// Problem constants
constexpr int T = 2048;
constexpr int B = 8;
constexpr int C = 1024;
constexpr int H = 16;
constexpr int K = 31;
constexpr int BC = B * C;            // 8192, stride between time steps

// Tiling: TT=64 cuts halo read-amplification to (30+64)/64 = 1.47x
// (R11 at TT=32 was 1.9x and measured request-BW-bound at ~6.6 TB/s).
constexpr int TT = 64;               // outputs per thread
constexpr int NB = K - 1 + TT;       // 93 window slots
constexpr int BLOCK = 256;
constexpr int BLK_PER_CHUNK = BC / BLOCK;    // 32
constexpr int NCHUNK = T / TT;               // 32
constexpr int NBLK = BLK_PER_CHUNK * NCHUNK; // 1024 blocks -> 4/CU

// ---------------------------------------------------------------------------
// out[t,b,c] = sum_{d=0..K-1} wr[d] * x[t-d, b, c] + bias[c]
// wr[d] = softmax(w[h])[K-1-d]  (head h is wave-uniform).
//
// Exact R11 structure (28.0 us proven) with TT=32 -> 64 as the ONLY change.
// Loads: asm-volatile global_load_dword, 64-bit per-load address, pinned
// issue order; compiler's exact per-register vmcnt tracking handles drains
// (R11: partial batching, VGPR 52, single-exposure pattern — sufficient,
// since the kernel is request-volume-bound, not latency-bound).
// R12's crash combo (saddr asm + launch_bounds VGPR cap + forced liveness)
// is reverted wholesale.
// Stores: scalar nontemporal (proven WRITE_SIZE == 65536 KB exactly).
// ---------------------------------------------------------------------------
__global__ __launch_bounds__(BLOCK) void lconv_tbc_kernel(
        const float* __restrict__ x,
        const float* __restrict__ w,
        const float* __restrict__ bias,
        float* __restrict__ out) {
    const int tid = threadIdx.x;
    const int cb = blockIdx.x & (BLK_PER_CHUNK - 1);   // bc slice (fastest)
    const int chunk = blockIdx.x / BLK_PER_CHUNK;      // time chunk
    const int bc = cb * BLOCK + tid;                   // [0, BC)
    const int c = bc & (C - 1);
    const int h = __builtin_amdgcn_readfirstlane(c >> 6);  // wave-uniform head

    const int t0 = chunk * TT;
    const float* col = x + bc;          // per-lane column base

    // bias load first (drains before/with the window).
    const float bi = bias[c];

    // ---- Issue the window as pinned-order asm loads: buf[j] = x[t0-30+j] ----
    float buf[NB];
    if (chunk == 0) {
        #pragma unroll
        for (int j = 0; j < K - 1; ++j) buf[j] = 0.0f;
        #pragma unroll
        for (int j = K - 1; j < NB; ++j) {
            const float* a = col + (t0 + (j - (K - 1))) * BC;
            asm volatile("global_load_dword %0, %1, off"
                         : "=v"(buf[j]) : "v"(a));
        }
    } else {
        #pragma unroll
        for (int j = 0; j < NB; ++j) {
            const float* a = col + (t0 - (K - 1) + j) * BC;
            asm volatile("global_load_dword %0, %1, off"
                         : "=v"(buf[j]) : "v"(a));
        }
    }

    // ---- Register-lean softmax in the load shadow (taps -> SGPRs) ----
    float tap[K];
    #pragma unroll
    for (int k = 0; k < K; ++k)
        tap[k] = __uint_as_float(__builtin_amdgcn_readfirstlane(
            __float_as_uint(w[h * K + k])));
    float m = tap[0];
    #pragma unroll
    for (int k = 1; k < K; ++k) m = fmaxf(m, tap[k]);
    float s = 0.0f;
    #pragma unroll
    for (int k = 0; k < K; ++k) s += __expf(tap[k] - m);
    const float inv = 1.0f / s;
    float wr[K];   // reversed, wave-uniform -> SGPRs
    #pragma unroll
    for (int d = 0; d < K; ++d)
        wr[d] = __uint_as_float(__builtin_amdgcn_readfirstlane(
            __float_as_uint(__expf(tap[K - 1 - d] - m) * inv)));

    // ---- 64 outputs x 31 FMAs; buf consumed oldest-first so the
    // compiler's exact vmcnt tracking drains the queue incrementally. ----
    const int base = t0 * BC + bc;      // element index fits int (max 16.8M)
    #pragma unroll
    for (int u = 0; u < TT; ++u) {
        float acc = bi;
        #pragma unroll
        for (int d = 0; d < K; ++d)
            acc = fmaf(wr[d], buf[K - 1 + u - d], acc);
        __builtin_nontemporal_store(acc, &out[base + u * BC]);
    }
}

extern "C" void kernel_launch(void* const* d_in, const int* in_sizes, int n_in,
                              void* d_out, int out_size, void* d_ws, size_t ws_size,
                              hipStream_t stream) {
    const float* x = (const float*)d_in[0];      // [T, B, C]
    const float* w = (const float*)d_in[1];      // [H, 1, K]
    const float* bias = (const float*)d_in[2];   // [C]
    float* out = (float*)d_out;                  // [T, B, C]

    lconv_tbc_kernel<<<dim3(NBLK), dim3(BLOCK), 0, stream>>>(x, w, bias, out);
}

// Round 14
// 28.183 us; speedup vs baseline: 1.1068x; 1.1068x over previous
//
#include <hip/hip_runtime.h>
#include <stdint.h>

// Problem constants
constexpr int T = 2048;
constexpr int B = 8;
constexpr int C = 1024;
constexpr int H = 16;
constexpr int K = 31;
constexpr int BC = B * C;            // 8192 floats per time row
constexpr int PB = BC / 2;           // 4096 float2 pairs per time row

// Tiling: thread owns a CHANNEL PAIR (f32x2) x TT=32 time steps.
// Burst doubling at constant traffic: loads dwordx2 (512 B/wave-instr),
// stores f32x2 (512 B/wave-instr). A/B: vs R13 same waves 2x burst;
// vs R11 same traffic 2x burst half waves.
constexpr int TT = 32;               // outputs per thread
constexpr int NB = K - 1 + TT;       // 62 window slots (f32x2 each)
constexpr int BLOCK = 256;
constexpr int NSLICE = PB / BLOCK;   // 16 pair-slices
constexpr int NCHUNK = T / TT;       // 64
constexpr int NBLK = NSLICE * NCHUNK; // 1024 blocks

typedef float f32x2 __attribute__((ext_vector_type(2)));

// ---------------------------------------------------------------------------
// out[t,p] = sum_{d} wr[d] * x[t-d, p] + bias[p]   (p = channel pair)
// Pair p covers channels c=2*(p&511), c+1 -> same head (64 | head width).
// Wave spans 2 heads (lanes 0-31 / 32-63) -> per-lane weights in VGPRs.
// ---------------------------------------------------------------------------
__global__ __launch_bounds__(BLOCK) void lconv_tbc_kernel(
        const float* __restrict__ x,
        const float* __restrict__ w,
        const float* __restrict__ bias,
        float* __restrict__ out) {
    const int tid = threadIdx.x;
    const int slice = blockIdx.x & (NSLICE - 1);   // pair slice (fastest)
    const int chunk = blockIdx.x / NSLICE;         // time chunk
    const int p = slice * BLOCK + tid;             // [0, PB)
    const int c = (p & 511) * 2;                   // channel of .x
    const int h = c >> 6;                          // per-lane head

    const int t0 = chunk * TT;
    const f32x2* colp = (const f32x2*)x + p;       // pair column base

    const f32x2 bi = ((const f32x2*)bias)[p & 511];

    // ---- Issue the window as pinned-order asm dwordx2 loads ----
    // buf[j] = x[t0 - 30 + j] (pair)
    f32x2 buf[NB];
    if (chunk == 0) {
        #pragma unroll
        for (int j = 0; j < K - 1; ++j) buf[j] = (f32x2){0.f, 0.f};
        #pragma unroll
        for (int j = K - 1; j < NB; ++j) {
            const f32x2* a = colp + (t0 + (j - (K - 1))) * PB;
            asm volatile("global_load_dwordx2 %0, %1, off"
                         : "=v"(buf[j]) : "v"(a));
        }
    } else {
        #pragma unroll
        for (int j = 0; j < NB; ++j) {
            const f32x2* a = colp + (t0 - (K - 1) + j) * PB;
            asm volatile("global_load_dwordx2 %0, %1, off"
                         : "=v"(buf[j]) : "v"(a));
        }
    }

    // ---- Per-lane softmax in the load shadow (weights stay in VGPRs) ----
    float wv[K];
    #pragma unroll
    for (int k = 0; k < K; ++k) wv[k] = w[h * K + k];
    float m = wv[0];
    #pragma unroll
    for (int k = 1; k < K; ++k) m = fmaxf(m, wv[k]);
    float s = 0.0f;
    #pragma unroll
    for (int k = 0; k < K; ++k) {
        wv[k] = __expf(wv[k] - m);
        s += wv[k];
    }
    const float inv = 1.0f / s;
    float wr[K];                                   // reversed taps
    #pragma unroll
    for (int d = 0; d < K; ++d) wr[d] = wv[K - 1 - d] * inv;

    // ---- 32 outputs x 31 pair-FMAs (fusible to v_pk_fma_f32) ----
    f32x2* outp = (f32x2*)out + t0 * PB + p;
    #pragma unroll
    for (int u = 0; u < TT; ++u) {
        f32x2 acc = bi;
        #pragma unroll
        for (int d = 0; d < K; ++d) {
            const f32x2 v = buf[K - 1 + u - d];
            acc.x = fmaf(wr[d], v.x, acc.x);
            acc.y = fmaf(wr[d], v.y, acc.y);
        }
        outp[u * PB] = acc;   // plain store: 512 B/wave contiguous
    }
}

extern "C" void kernel_launch(void* const* d_in, const int* in_sizes, int n_in,
                              void* d_out, int out_size, void* d_ws, size_t ws_size,
                              hipStream_t stream) {
    const float* x = (const float*)d_in[0];      // [T, B, C]
    const float* w = (const float*)d_in[1];      // [H, 1, K]
    const float* bias = (const float*)d_in[2];   // [C]
    float* out = (float*)d_out;                  // [T, B, C]

    lconv_tbc_kernel<<<dim3(NBLK), dim3(BLOCK), 0, stream>>>(x, w, bias, out);
}